// Round 5
// baseline (351.436 us; speedup 1.0000x reference)
//
#include <hip/hip_runtime.h>

// sparselinear: out[b*S + s] = sum_{e: row[e]==s} x[b*G + col[e]] * W[e] + bias[s]
// B=64 (== wavefront), G=20000, S=200000, NNZ=2e6.
//
// ONE grid-resident kernel (plus a 4-byte memset), graph-capture safe:
//   phase 1 (grid-strided over 313+977 work items):
//     - transpose x [B,G] -> xTh [G,B] bf16 (2.56MB, L2-resident gathers)
//     - pass1: counting sort of 2048-edge chunks into 64-row bins (3125):
//       LDS hist[3584] -> wave-shfl scan -> LDS scatter (edges held in
//       registers) -> coalesced dump + per-chunk U16 LOCAL-START table
//       (6.1MB, 32 bins/cacheline; R4's u32 table cost compute +8MB FETCH).
//   device-scope grid barrier (threadfence + agent-scope atomic counter;
//     NB from hipOccupancyMaxActiveBlocksPerMultiprocessor => co-residency
//     guaranteed; grid-stride keeps ANY NB correct).
//   phase 2 (grid-strided over 3125 bins, XCD-swizzled):
//     gather bin's ~640 edges from 977 runs, 64-row LDS sort (4-replica
//     hist + wave scan), proven quad-lockstep PROC loop, 16KB LDS
//     transpose epilogue overlaying the staging buffer.
//
// R4 post-mortem: total-minus-compute ~= 97us while prep dispatch provably
// < 82us and models say ~25-30us => suspect inter-dispatch overhead and/or
// hidden prep cost. Fusing to one dispatch removes the former and makes the
// latter directly visible in top-5.

#define WAVE 64
#define CHUNK 2048
#define RBITS 6                 // 64 rows per bin
#define BINROWS 64
#define NBIN_PAD 3584           // 256*14 >= nbin+1 = 3126
#define CAP_BIN 896             // max edges/bin: mean 640 + ~10 sigma
#define SMEM_BYTES 30752        // max(prep 30736, compute 26128), 16-aligned

#define RL(v, i)  __builtin_amdgcn_readlane((int)(v), (i))
#define RLF(v, i) __int_as_float(__builtin_amdgcn_readlane(__float_as_int(v), (i)))

__device__ __forceinline__ int swz(int r, int b) {
    return (r << 6) + (b ^ (r & 63));   // tile[64][64], XOR-swizzled (2-way free)
}

__device__ __forceinline__ unsigned short f2bf(float f) {
    unsigned u = __float_as_uint(f);
    unsigned r = (u + 0x7fffu + ((u >> 16) & 1u)) >> 16;   // RTNE
    return (unsigned short)r;
}

// Device-scope grid barrier (Guideline 16): release-fence + agent atomic.
__device__ __forceinline__ void grid_barrier(int* bar, int nb) {
    __syncthreads();
    if (threadIdx.x == 0) {
        __threadfence();                       // device-scope release
        atomicAdd(bar, 1);                     // device-scope by default
        while (__hip_atomic_load(bar, __ATOMIC_ACQUIRE,
                                 __HIP_MEMORY_SCOPE_AGENT) < nb)
            __builtin_amdgcn_s_sleep(2);
    }
    __syncthreads();
}

// gather+fmac one broadcast edge for one row's accumulator
#define PROC(Er, ar, ii)                                                      \
    {                                                                         \
        const int   k_ = RL((Er).x, (ii));                                    \
        const float w_ = __int_as_float(RL((Er).y, (ii)));                    \
        const float v_ = __uint_as_float(                                     \
            (unsigned)*(const unsigned short*)(xb + k_ + lane2) << 16);       \
        (ar) += v_ * w_;                                                      \
    }

__global__ __launch_bounds__(256) void fused_kernel(
        const float* __restrict__ x, unsigned short* __restrict__ xTh,
        int G, int tgrid,
        const int* __restrict__ row, const int* __restrict__ col,
        const float* __restrict__ w,
        uint2* __restrict__ sedge1, unsigned short* __restrict__ seg16,
        const float* __restrict__ bias, float* __restrict__ out,
        int S, int nnz, int nbin, int nchunk, int NB, int* __restrict__ bar) {
    __shared__ __align__(16) char smem[SMEM_BYTES];
    const int t    = threadIdx.x;
    const int lane = t & 63;
    const int wv   = t >> 6;                   // 0..3

    // ================= phase 1: transpose + pass1 =================
    const int nwork1 = tgrid + nchunk;
    for (int itw = blockIdx.x; itw < nwork1; itw += NB) {
        __syncthreads();                       // smem reuse across iterations
        if (itw < tgrid) {
            // ---- transpose sub-block ----
            float (*tile)[65] = (float (*)[65])smem;
            const int g0 = itw * 64;
            {
                const int j  = t & 63;
                const int b0 = t >> 6;
                if (g0 + j < G) {
                    #pragma unroll
                    for (int it = 0; it < 16; ++it) {
                        const int b = b0 + it * 4;
                        tile[j][b] = x[(size_t)b * G + g0 + j];
                    }
                }
            }
            __syncthreads();
            {
                const int b  = t & 63;
                const int j0 = t >> 6;
                #pragma unroll
                for (int it = 0; it < 16; ++it) {
                    const int j = j0 + it * 4;
                    if (g0 + j < G)
                        xTh[(size_t)(g0 + j) * WAVE + b] = f2bf(tile[j][b]);
                }
            }
        } else {
            // ---- pass1 sub-block: chunk counting sort ----
            uint2* stage = (uint2*)smem;                     // 16 KB
            int*   hist  = (int*)(smem + CHUNK * 8);         // 14 KB
            int*   wpart = (int*)(smem + CHUNK * 8 + NBIN_PAD * 4);
            const int blk  = itw - tgrid;
            const int e0   = blk * CHUNK;
            const bool full = (e0 + CHUNK <= nnz);
            const int M    = full ? CHUNK : (nnz - e0);

            for (int j = t; j < NBIN_PAD; j += 256) hist[j] = 0;
            __syncthreads();

            int4 ra, rb, ca, cb; float4 wa, wb;
            if (full) {
                // A) 8 edges/thread into registers + count
                const int4*   rv = (const int4*)(row + e0);
                const int4*   cv = (const int4*)(col + e0);
                const float4* wf = (const float4*)(w + e0);
                ra = rv[t]; rb = rv[t + 256];
                ca = cv[t]; cb = cv[t + 256];
                wa = wf[t]; wb = wf[t + 256];
                atomicAdd(&hist[ra.x >> RBITS], 1);
                atomicAdd(&hist[ra.y >> RBITS], 1);
                atomicAdd(&hist[ra.z >> RBITS], 1);
                atomicAdd(&hist[ra.w >> RBITS], 1);
                atomicAdd(&hist[rb.x >> RBITS], 1);
                atomicAdd(&hist[rb.y >> RBITS], 1);
                atomicAdd(&hist[rb.z >> RBITS], 1);
                atomicAdd(&hist[rb.w >> RBITS], 1);
            } else {
                for (int k = 0; k < CHUNK / 256; ++k) {
                    const int i = k * 256 + t;
                    if (i < M) atomicAdd(&hist[row[e0 + i] >> RBITS], 1);
                }
            }
            __syncthreads();

            // B) scan: thread t owns bins [14t,14t+14); u16 local starts
            {
                int c[14];
                int p = 0;
                #pragma unroll
                for (int j = 0; j < 14; ++j) { c[j] = hist[t * 14 + j]; p += c[j]; }
                int incl = p;
                #pragma unroll
                for (int d = 1; d < 64; d <<= 1) {
                    const int u = __shfl_up(incl, d);
                    if (lane >= d) incl += u;
                }
                if (lane == 63) wpart[wv] = incl;
                __syncthreads();
                int base = incl - p;
                #pragma unroll
                for (int ww = 0; ww < 4; ++ww)
                    if (ww < wv) base += wpart[ww];
                unsigned short* st = seg16 + (size_t)blk * (size_t)(nbin + 1);
                int run = base;
                #pragma unroll
                for (int j = 0; j < 14; ++j) {
                    const int bj = t * 14 + j;
                    hist[bj] = run;                  // scatter cursor (local)
                    if (bj <= nbin) st[bj] = (unsigned short)run;
                    run += c[j];
                }
            }
            __syncthreads();

            // C) scatter into LDS staging from registers
#define PUT(r_, c_, w_)                                                       \
    {                                                                         \
        const int pos = atomicAdd(&hist[(r_) >> RBITS], 1);                   \
        stage[pos] = make_uint2(((unsigned)((r_) & 63) << 15) |               \
                                (unsigned)(c_), __float_as_uint(w_));         \
    }
            if (full) {
                PUT(ra.x, ca.x, wa.x) PUT(ra.y, ca.y, wa.y)
                PUT(ra.z, ca.z, wa.z) PUT(ra.w, ca.w, wa.w)
                PUT(rb.x, cb.x, wb.x) PUT(rb.y, cb.y, wb.y)
                PUT(rb.z, cb.z, wb.z) PUT(rb.w, cb.w, wb.w)
            } else {
                for (int k = 0; k < CHUNK / 256; ++k) {
                    const int i = k * 256 + t;
                    if (i < M) {
                        const int r = row[e0 + i];
                        PUT(r, col[e0 + i], w[e0 + i])
                    }
                }
            }
#undef PUT
            __syncthreads();

            // D) coalesced contiguous dump
            if (full) {
                const uint4* sg4 = (const uint4*)stage;
                uint4* o4 = (uint4*)(sedge1 + e0);
                #pragma unroll
                for (int k = 0; k < CHUNK / 512; ++k)
                    o4[k * 256 + t] = sg4[k * 256 + t];
            } else {
                for (int j = t; j < M; j += 256) sedge1[e0 + j] = stage[j];
            }
        }
    }

    // ================= grid barrier =================
    grid_barrier(bar, NB);

    // ================= phase 2: compute =================
    float* tile  = (float*)smem;                       // 16 KB
    uint2* eds2  = (uint2*)(smem + 16384);             // 7 KB
    int (*rcnt)[BINROWS] = (int (*)[BINROWS])(smem + 23552);
    int (*cur)[BINROWS]  = (int (*)[BINROWS])(smem + 24576);
    int* rstart = (int*)(smem + 25600);
    int* rend   = (int*)(smem + 25856);
    int* spart  = (int*)(smem + 26112);
    uint2* eds1 = (uint2*)smem;                        // aliases tile (2048 cap)

    const char* xb = (const char*)xTh;
    const int lane2 = lane * 2;
    const size_t stride = (size_t)(nbin + 1);

    for (int iw = blockIdx.x; iw < nbin; iw += NB) {
        __syncthreads();                       // smem reuse across iterations

        // bijective chunked XCD swizzle: co-temporal blocks -> same XCD
        const int q8 = nbin >> 3, r8 = nbin & 7;
        const int xcd = iw & 7, off = iw >> 3;
        const int b = (xcd < r8 ? xcd * (q8 + 1)
                                : r8 * (q8 + 1) + (xcd - r8) * q8) + off;
        const int r0 = b << RBITS;

        if (t < BINROWS) {
            rcnt[0][t] = 0; rcnt[1][t] = 0; rcnt[2][t] = 0; rcnt[3][t] = 0;
        }

        // A) per-chunk run fetch (thread t -> chunks t, t+256, t+512, t+768)
        int st0 = 0, n0_ = 0, st1 = 0, n1_ = 0;
        int st2 = 0, n2_ = 0, st3 = 0, n3_ = 0;
        {
            if (t < nchunk) {
                const unsigned short* p = seg16 + (size_t)t * stride + b;
                st0 = t * CHUNK + (int)p[0]; n0_ = (int)p[1] - (int)p[0];
            }
            if (t + 256 < nchunk) {
                const unsigned short* p = seg16 + (size_t)(t + 256) * stride + b;
                st1 = (t + 256) * CHUNK + (int)p[0]; n1_ = (int)p[1] - (int)p[0];
            }
            if (t + 512 < nchunk) {
                const unsigned short* p = seg16 + (size_t)(t + 512) * stride + b;
                st2 = (t + 512) * CHUNK + (int)p[0]; n2_ = (int)p[1] - (int)p[0];
            }
            if (t + 768 < nchunk) {
                const unsigned short* p = seg16 + (size_t)(t + 768) * stride + b;
                st3 = (t + 768) * CHUNK + (int)p[0]; n3_ = (int)p[1] - (int)p[0];
            }
        }
        const int nt = n0_ + n1_ + n2_ + n3_;
        int incl = nt;
        #pragma unroll
        for (int d = 1; d < 64; d <<= 1) {
            const int u = __shfl_up(incl, d);
            if (lane >= d) incl += u;
        }
        if (lane == 63) spart[wv] = incl;
        __syncthreads();
        int base = incl - nt;
        #pragma unroll
        for (int ww = 0; ww < 4; ++ww)
            if (ww < wv) base += spart[ww];
        int M = spart[0] + spart[1] + spart[2] + spart[3];
        if (M > CAP_BIN) M = CAP_BIN;          // statistically unreachable

        // B) gather this bin's edges into LDS (order within bin irrelevant)
        {
            int p = base;
            for (int k = 0; k < n0_; ++k, ++p)
                if (p < CAP_BIN) eds1[p] = sedge1[st0 + k];
            for (int k = 0; k < n1_; ++k, ++p)
                if (p < CAP_BIN) eds1[p] = sedge1[st1 + k];
            for (int k = 0; k < n2_; ++k, ++p)
                if (p < CAP_BIN) eds1[p] = sedge1[st2 + k];
            for (int k = 0; k < n3_; ++k, ++p)
                if (p < CAP_BIN) eds1[p] = sedge1[st3 + k];
        }
        __syncthreads();

        // C) row histogram (4 wave-private replicas)
        for (int i = t; i < M; i += 256)
            atomicAdd(&rcnt[wv][eds1[i].x >> 15], 1);
        __syncthreads();

        // D) 64-row scan + per-replica cursor bases (wave 0 only)
        if (t < BINROWS) {
            const int c0 = rcnt[0][t], c1 = rcnt[1][t];
            const int c2 = rcnt[2][t], c3 = rcnt[3][t];
            const int tot = c0 + c1 + c2 + c3;
            int inc2 = tot;
            #pragma unroll
            for (int d = 1; d < 64; d <<= 1) {
                const int u = __shfl_up(inc2, d);
                if (lane >= d) inc2 += u;
            }
            const int stt = inc2 - tot;
            rstart[t] = stt;
            rend[t]   = stt + tot;
            cur[0][t] = stt;
            cur[1][t] = stt + c0;
            cur[2][t] = stt + c0 + c1;
            cur[3][t] = stt + c0 + c1 + c2;
        }
        __syncthreads();

        // E) scatter sorted-by-row; key -> byte offset of bf16 xTh row
        for (int i = t; i < M; i += 256) {
            const uint2 e = eds1[i];
            const int r = (int)(e.x >> 15);
            const int pos = atomicAdd(&cur[wv][r], 1);
            eds2[pos] = make_uint2((e.x & 0x7fffu) << 7, e.y);
        }
        __syncthreads();

        // F) quad-lockstep compute: wave wv -> rows [wv*16, wv*16+16)
        const int rw = r0 + wv * 16;
        float bv = 0.f;
        if (lane < 16 && rw + lane < S) bv = bias[rw + lane];

        #pragma unroll
        for (int qd = 0; qd < 4; ++qd) {
            const int rl = wv * 16 + qd * 4;
            int s0 = rstart[rl + 0], e0g = rend[rl + 0];
            int s1 = rstart[rl + 1], e1g = rend[rl + 1];
            int s2 = rstart[rl + 2], e2g = rend[rl + 2];
            int s3 = rstart[rl + 3], e3g = rend[rl + 3];
            float a0 = 0.f, a1 = 0.f, a2 = 0.f, a3 = 0.f;
            while ((s0 < e0g) || (s1 < e1g) || (s2 < e2g) || (s3 < e3g)) {
                const int m0 = min(WAVE, e0g - s0);
                const int m1 = min(WAVE, e1g - s1);
                const int m2 = min(WAVE, e2g - s2);
                const int m3 = min(WAVE, e3g - s3);
                uint2 E0 = make_uint2(0u, 0u), E1 = make_uint2(0u, 0u);
                uint2 E2 = make_uint2(0u, 0u), E3 = make_uint2(0u, 0u);
                if (lane < m0) E0 = eds2[s0 + lane];
                if (lane < m1) E1 = eds2[s1 + lane];
                if (lane < m2) E2 = eds2[s2 + lane];
                if (lane < m3) E3 = eds2[s3 + lane];
                const int mm = max(max(m0, m1), max(m2, m3));
                int i = 0;
                for (; i + 2 <= mm; i += 2) {
                    PROC(E0, a0, i) PROC(E1, a1, i)
                    PROC(E2, a2, i) PROC(E3, a3, i)
                    PROC(E0, a0, i + 1) PROC(E1, a1, i + 1)
                    PROC(E2, a2, i + 1) PROC(E3, a3, i + 1)
                }
                if (i < mm) {
                    PROC(E0, a0, i) PROC(E1, a1, i)
                    PROC(E2, a2, i) PROC(E3, a3, i)
                }
                s0 += max(m0, 0); s1 += max(m1, 0);
                s2 += max(m2, 0); s3 += max(m3, 0);
            }
            tile[swz(rl + 0, lane)] = a0 + RLF(bv, qd * 4 + 0);
            tile[swz(rl + 1, lane)] = a1 + RLF(bv, qd * 4 + 1);
            tile[swz(rl + 2, lane)] = a2 + RLF(bv, qd * 4 + 2);
            tile[swz(rl + 3, lane)] = a3 + RLF(bv, qd * 4 + 3);
        }
        __syncthreads();

        // G) coalesced epilogue: wave wv -> batches [wv*16, wv*16+16)
        const int srow = r0 + lane;
        #pragma unroll
        for (int k = 0; k < 16; ++k) {
            const int bb = wv * 16 + k;
            if (srow < S) out[(size_t)bb * S + srow] = tile[swz(lane, bb)];
        }
    }
}

extern "C" void kernel_launch(void* const* d_in, const int* in_sizes, int n_in,
                              void* d_out, int out_size, void* d_ws, size_t ws_size,
                              hipStream_t stream) {
    const float* x    = (const float*)d_in[0];
    const float* W    = (const float*)d_in[1];
    const float* bias = (const float*)d_in[2];
    const int*   idx  = (const int*)d_in[3];

    const int NNZ = in_sizes[1];
    const int S   = in_sizes[2];
    const int B   = out_size / S;        // 64
    const int G   = in_sizes[0] / B;     // 20000
    const int* rowi = idx;
    const int* coli = idx + NNZ;
    float* out = (float*)d_out;

    const int nbin   = (S + BINROWS - 1) >> RBITS;        // 3125
    const int nchunk = (NNZ + CHUNK - 1) / CHUNK;         // 977 (<= 1024)
    const int tgrid  = (G + 63) / 64;                     // 313

    // workspace layout (256B-aligned slabs), ~25 MB total
    char* ws = (char*)d_ws;
    size_t o = 0;
    auto alloc = [&](size_t bytes) {
        void* p = ws + o;
        o = (o + bytes + 255) & ~(size_t)255;
        return p;
    };
    int* bar = (int*)alloc(256);
    unsigned short* xTh = (unsigned short*)alloc((size_t)G * B * sizeof(unsigned short));
    uint2* sedge1 = (uint2*)alloc((size_t)NNZ * sizeof(uint2));
    unsigned short* seg16 = (unsigned short*)alloc(
        (size_t)nchunk * (size_t)(nbin + 1) * sizeof(unsigned short));
    (void)ws_size; (void)n_in;

    // co-resident block count from the occupancy API (deadlock-safe);
    // grid-stride keeps any NB correct.
    static int NB = -1;
    if (NB < 0) {
        int dev = 0;
        (void)hipGetDevice(&dev);
        int ncu = 0;
        if (hipDeviceGetAttribute(&ncu, hipDeviceAttributeMultiprocessorCount,
                                  dev) != hipSuccess || ncu <= 0)
            ncu = 256;
        int bpc = 0;
        if (hipOccupancyMaxActiveBlocksPerMultiprocessor(&bpc, fused_kernel,
                                                         256, 0) != hipSuccess ||
            bpc < 1)
            bpc = 1;
        NB = ncu * bpc;
        if (NB > 8192) NB = 8192;
    }

    hipMemsetAsync(bar, 0, sizeof(int), stream);
    fused_kernel<<<NB, 256, 0, stream>>>(
        x, xTh, G, tgrid, rowi, coli, W, sedge1, seg16, bias, out,
        S, NNZ, nbin, nchunk, NB, bar);
}

// Round 6
// 245.039 us; speedup vs baseline: 1.4342x; 1.4342x over previous
//
#include <hip/hip_runtime.h>

// sparselinear: out[b*S + s] = sum_{e: row[e]==s} x[b*G + col[e]] * W[e] + bias[s]
// B=64 (== wavefront), G=20000, S=200000, NNZ=2e6.
//
// R5 post-mortem: single fused dispatch measured 265us vs bench 351us =>
// ~86us FIXED per-iteration harness overhead in every round's dur_us.
// => prep was never ~90us (that was overhead double-counted); the grid
// barrier's acquire-spin (L2-invalidating) + cold caches made R5 worse.
// Revert to R3's proven 3-dispatch structure; attack compute instead.
//
// Pipeline (graph-capture safe, all on `stream`):
//   1. transpose x [B,G] -> xTh [G,B] in BF16 (2.56MB, L2-resident gathers)
//   2. pass1 (R3-proven structure, RBITS 6->5): counting sort of 8192-edge
//      chunks into 32-row bins (6250): LDS hist[6656] -> wave-shfl scan
//      (13 bins/thread) -> LDS scatter -> coalesced dump + u32 START table.
//   3. compute: one 256-thread block per 32-row bin (6250 blocks, 4/CU).
//      SORT-FREE: 4 per-wave private 8KB LDS tiles [32r][64b] f32 (no LDS
//      atomics -- the in-block row-sort's ds_add_rtn was ~17us of R3's 72).
//      Edges processed in PAIRS: lanes 0-31 edge A, 32-63 edge B; one
//      dword gather = 2 bf16 batches/lane; one b64 tile RMW (XOR-swizzled
//      pair index, conflict-free). Same-row pair collision (P~3%) handled
//      by wave-uniform branch + shfl_xor(32) combine. Epilogue merges 4
//      tiles + bias, conflict-free column reads, coalesced stores.

#define WAVE 64
#define CHUNK 8192
#define RBITS 5                 // 32 rows per bin
#define BINROWS 32
#define NBIN_PAD 6656           // 512*13 >= nbin+1 = 6251
#define CAP_BIN 576             // max edges/bin: mean 320 + ~14 sigma (64-mult)

#define RL(v, i)  __builtin_amdgcn_readlane((int)(v), (i))

__device__ __forceinline__ unsigned short f2bf(float f) {
    unsigned u = __float_as_uint(f);
    unsigned r = (u + 0x7fffu + ((u >> 16) & 1u)) >> 16;   // RTNE
    return (unsigned short)r;
}

__global__ void transpose64_kernel(const float* __restrict__ x,
                                   unsigned short* __restrict__ xTh, int G) {
    __shared__ float tile[64][65];
    const int t  = threadIdx.x;
    const int g0 = blockIdx.x * 64;
    {
        const int j  = t & 63;
        const int b0 = t >> 6;
        if (g0 + j < G) {
            #pragma unroll
            for (int it = 0; it < 16; ++it) {
                const int b = b0 + it * 4;
                tile[j][b] = x[(size_t)b * G + g0 + j];
            }
        }
    }
    __syncthreads();
    {
        const int b  = t & 63;
        const int j0 = t >> 6;
        #pragma unroll
        for (int it = 0; it < 16; ++it) {
            const int j = j0 + it * 4;
            if (g0 + j < G) xTh[(size_t)(g0 + j) * WAVE + b] = f2bf(tile[j][b]);
        }
    }
}

// Pass 1: per-chunk counting sort into 32-row bins. All global stores
// coalesced. Record: ((r & 31) << 15) | col.
// segtab[chunk*(nbin+1) + b] = global start of (chunk,bin) run.
__global__ __launch_bounds__(512) void pass1_kernel(
        const int* __restrict__ row, const int* __restrict__ col,
        const float* __restrict__ w, uint2* __restrict__ sedge1,
        unsigned* __restrict__ segtab, int nnz, int nbin) {
    __shared__ __align__(16) uint2 stage[CHUNK];   // 64 KB
    __shared__ int hist[NBIN_PAD];                 // 26 KB
    __shared__ int wpart[8];
    const int t    = threadIdx.x;
    const int lane = t & 63;
    const int wv   = t >> 6;
    const int e0   = blockIdx.x * CHUNK;
    const bool full = (e0 + CHUNK <= nnz);
    const int M    = full ? CHUNK : (nnz - e0);

    for (int j = t; j < NBIN_PAD; j += 512) hist[j] = 0;
    __syncthreads();

    // A) count
    if (full) {
        const int4* rv = (const int4*)(row + e0);
        #pragma unroll
        for (int k = 0; k < CHUNK / 2048; ++k) {
            const int4 r4 = rv[k * 512 + t];
            atomicAdd(&hist[r4.x >> RBITS], 1);
            atomicAdd(&hist[r4.y >> RBITS], 1);
            atomicAdd(&hist[r4.z >> RBITS], 1);
            atomicAdd(&hist[r4.w >> RBITS], 1);
        }
    } else {
        for (int k = 0; k < CHUNK / 512; ++k) {
            const int i = k * 512 + t;
            if (i < M) atomicAdd(&hist[row[e0 + i] >> RBITS], 1);
        }
    }
    __syncthreads();

    // B) scan: thread t owns bins [13t, 13t+13); wave shfl-scan + cross-wave
    {
        int c[13];
        int p = 0;
        #pragma unroll
        for (int j = 0; j < 13; ++j) { c[j] = hist[t * 13 + j]; p += c[j]; }
        int incl = p;
        #pragma unroll
        for (int d = 1; d < 64; d <<= 1) {
            const int u = __shfl_up(incl, d);
            if (lane >= d) incl += u;
        }
        if (lane == 63) wpart[wv] = incl;
        __syncthreads();
        int base = incl - p;
        #pragma unroll
        for (int ww = 0; ww < 8; ++ww)
            if (ww < wv) base += wpart[ww];
        unsigned* st = segtab + (size_t)blockIdx.x * (size_t)(nbin + 1);
        int run = base;
        #pragma unroll
        for (int j = 0; j < 13; ++j) {
            const int bj = t * 13 + j;
            hist[bj] = run;                         // scatter cursor (local)
            if (bj <= nbin) st[bj] = (unsigned)(e0 + run);
            run += c[j];
        }
    }
    __syncthreads();

    // C) scatter into LDS staging (chunk re-read is L2-hot)
    if (full) {
        const int4*   rv = (const int4*)(row + e0);
        const int4*   cv = (const int4*)(col + e0);
        const float4* wf = (const float4*)(w + e0);
        #pragma unroll
        for (int k = 0; k < CHUNK / 2048; ++k) {
            const int4   r4 = rv[k * 512 + t];
            const int4   c4 = cv[k * 512 + t];
            const float4 w4 = wf[k * 512 + t];
            {
                const int pos = atomicAdd(&hist[r4.x >> RBITS], 1);
                stage[pos] = make_uint2(((unsigned)(r4.x & (BINROWS - 1)) << 15) |
                                        (unsigned)c4.x, __float_as_uint(w4.x));
            }
            {
                const int pos = atomicAdd(&hist[r4.y >> RBITS], 1);
                stage[pos] = make_uint2(((unsigned)(r4.y & (BINROWS - 1)) << 15) |
                                        (unsigned)c4.y, __float_as_uint(w4.y));
            }
            {
                const int pos = atomicAdd(&hist[r4.z >> RBITS], 1);
                stage[pos] = make_uint2(((unsigned)(r4.z & (BINROWS - 1)) << 15) |
                                        (unsigned)c4.z, __float_as_uint(w4.z));
            }
            {
                const int pos = atomicAdd(&hist[r4.w >> RBITS], 1);
                stage[pos] = make_uint2(((unsigned)(r4.w & (BINROWS - 1)) << 15) |
                                        (unsigned)c4.w, __float_as_uint(w4.w));
            }
        }
    } else {
        for (int k = 0; k < CHUNK / 512; ++k) {
            const int i = k * 512 + t;
            if (i < M) {
                const int r = row[e0 + i];
                const int pos = atomicAdd(&hist[r >> RBITS], 1);
                stage[pos] = make_uint2(((unsigned)(r & (BINROWS - 1)) << 15) |
                                        (unsigned)col[e0 + i],
                                        __float_as_uint(w[e0 + i]));
            }
        }
    }
    __syncthreads();

    // D) coalesced contiguous dump
    {
        const uint4* sg4 = (const uint4*)stage;
        uint4* o4 = (uint4*)(sedge1 + e0);
        for (int j = t; j < (M >> 1); j += 512) o4[j] = sg4[j];
        if ((M & 1) && t == 0) sedge1[e0 + M - 1] = stage[M - 1];
    }
}

// Compute: one block per 32-row bin. Sort-free per-wave LDS tile
// accumulation; edges processed in half-wave pairs.
__global__ __launch_bounds__(256) void compute_kernel(
        const unsigned short* __restrict__ xTh,
        const uint2* __restrict__ sedge1,
        const unsigned* __restrict__ segtab,
        const float* __restrict__ bias,
        float* __restrict__ out, int S, int nchunk, int nbin) {
    __shared__ float tiles[4 * 2048];      // 32 KB: per-wave [32r][64b] f32
    __shared__ uint2 eds[CAP_BIN];         // 4.5 KB
    __shared__ int   spart[4];

    const int t    = threadIdx.x;
    const int lane = t & 63;
    const int wv   = t >> 6;               // 0..3
    const int l31  = lane & 31;
    const int half = lane >> 5;

    // bijective chunked XCD swizzle (L2-local sedge1 runs + segtab lines)
    const int q8 = nbin >> 3, r8 = nbin & 7;
    const int xcd = (int)blockIdx.x & 7, off = (int)blockIdx.x >> 3;
    const int b = (xcd < r8 ? xcd * (q8 + 1) : r8 * (q8 + 1) + (xcd - r8) * q8)
                  + off;
    const int r0 = b << RBITS;

    // zero this wave's tile (512 float4)
    {
        float4* tz = (float4*)(tiles + wv * 2048);
        #pragma unroll
        for (int k = 0; k < 8; ++k) tz[k * 64 + lane] = make_float4(0, 0, 0, 0);
    }

    // A) segment fetch (nchunk <= 256: one per thread) + block scan
    int st = 0, cnt = 0;
    if (t < nchunk) {
        const unsigned* p = segtab + (size_t)t * (size_t)(nbin + 1) + b;
        const unsigned s0 = p[0];
        st = (int)s0; cnt = (int)(p[1] - s0);
    }
    int incl = cnt;
    #pragma unroll
    for (int d = 1; d < 64; d <<= 1) {
        const int u = __shfl_up(incl, d);
        if (lane >= d) incl += u;
    }
    if (lane == 63) spart[wv] = incl;
    __syncthreads();
    int base = incl - cnt;
    #pragma unroll
    for (int ww = 0; ww < 4; ++ww)
        if (ww < wv) base += spart[ww];
    int M = spart[0] + spart[1] + spart[2] + spart[3];
    if (M > CAP_BIN) M = CAP_BIN;          // statistically unreachable

    // B) gather this bin's edges into LDS + zero-pad to 64-multiple
    for (int k = 0; k < cnt; ++k) {
        const int pp = base + k;
        if (pp < CAP_BIN) eds[pp] = sedge1[st + k];
    }
    const int Mp = (M + 63) & ~63;
    if (t < Mp - M) eds[M + t] = make_uint2(0u, 0u);  // key=0,w=0 -> +0
    __syncthreads();

    // C) paired accumulate: per 64-edge batch, 32 pairs; lanes 0-31 take
    //    edge A (2 batches each via dword bf16-pair gather), lanes 32-63
    //    edge B; one b64 tile RMW per lane (XOR-swizzled pair index).
    const char* xbl = (const char*)xTh + l31 * 4;
    float* T = tiles + wv * 2048;
    const int nb64 = Mp >> 6;
    for (int bt = wv; bt < nb64; bt += 4) {
        const uint2 E = eds[bt * 64 + lane];
        #pragma unroll
        for (int j = 0; j < 32; ++j) {
            const int kA = RL(E.x, 2 * j),  kB = RL(E.x, 2 * j + 1);
            const int wA = RL(E.y, 2 * j),  wB = RL(E.y, 2 * j + 1);
            const int key   = half ? kB : kA;
            const float w   = __int_as_float(half ? wB : wA);
            const int rA = kA >> 15, rB = kB >> 15;
            const int r  = half ? rB : rA;
            const unsigned cb = ((unsigned)key & 0x7fffu) << 7;
            const unsigned d  = *(const unsigned*)(xbl + cb);
            const float vlo = __uint_as_float(d << 16);
            const float vhi = __uint_as_float(d & 0xffff0000u);
            const float clo = vlo * w, chi = vhi * w;
            float* tp = T + (r << 6) + ((l31 ^ r) << 1);
            if (rA != rB) {                // wave-uniform branch
                float2 acc = *(float2*)tp;
                acc.x += clo; acc.y += chi;
                *(float2*)tp = acc;
            } else {                       // same-row pair: combine, half0 writes
                const float plo = __shfl_xor(clo, 32);
                const float phi = __shfl_xor(chi, 32);
                if (half == 0) {
                    float2 acc = *(float2*)tp;
                    acc.x += clo + plo; acc.y += chi + phi;
                    *(float2*)tp = acc;
                }
            }
        }
    }
    __syncthreads();

    // D) epilogue: merge 4 tiles + bias; wave wv -> batches [wv*16, wv*16+16)
    //    (2 per iter: half selects even/odd batch -> full 32-bank coverage)
    const int rr = l31;
    float bvr = 0.f;
    const bool rok = (r0 + rr < S);
    if (rok) bvr = bias[r0 + rr];
    #pragma unroll
    for (int k = 0; k < 8; ++k) {
        const int bb  = wv * 16 + k * 2 + half;
        const int p   = bb >> 1;
        const int sub = bb & 1;
        const int o   = (rr << 6) + ((p ^ rr) << 1) + sub;
        float v = tiles[o] + tiles[2048 + o] + tiles[4096 + o] + tiles[6144 + o]
                + bvr;
        if (rok) out[(size_t)bb * S + r0 + rr] = v;
    }
}

extern "C" void kernel_launch(void* const* d_in, const int* in_sizes, int n_in,
                              void* d_out, int out_size, void* d_ws, size_t ws_size,
                              hipStream_t stream) {
    const float* x    = (const float*)d_in[0];
    const float* W    = (const float*)d_in[1];
    const float* bias = (const float*)d_in[2];
    const int*   idx  = (const int*)d_in[3];

    const int NNZ = in_sizes[1];
    const int S   = in_sizes[2];
    const int B   = out_size / S;        // 64
    const int G   = in_sizes[0] / B;     // 20000
    const int* rowi = idx;
    const int* coli = idx + NNZ;
    float* out = (float*)d_out;

    const int nbin   = (S + BINROWS - 1) >> RBITS;        // 6250
    const int nchunk = (NNZ + CHUNK - 1) / CHUNK;         // 245 (<= 256)

    // workspace layout (256B-aligned slabs), ~25 MB total
    char* ws = (char*)d_ws;
    size_t o = 0;
    auto alloc = [&](size_t bytes) {
        void* p = ws + o;
        o = (o + bytes + 255) & ~(size_t)255;
        return p;
    };
    unsigned short* xTh = (unsigned short*)alloc((size_t)G * B * sizeof(unsigned short));
    uint2*    sedge1 = (uint2*)   alloc((size_t)NNZ * sizeof(uint2));
    unsigned* segtab = (unsigned*)alloc((size_t)nchunk * (size_t)(nbin + 1) *
                                        sizeof(unsigned));
    (void)ws_size; (void)n_in;

    const int tgrid = (G + 63) / 64;
    transpose64_kernel<<<tgrid, 256, 0, stream>>>(x, xTh, G);

    pass1_kernel<<<nchunk, 512, 0, stream>>>(rowi, coli, W, sedge1, segtab,
                                             NNZ, nbin);
    compute_kernel<<<nbin, 256, 0, stream>>>(xTh, sedge1, segtab, bias,
                                             out, S, nchunk, nbin);
}

// Round 7
// 158.425 us; speedup vs baseline: 2.2183x; 1.5467x over previous
//
#include <hip/hip_runtime.h>

// sparselinear: out[b*S + s] = sum_{e: row[e]==s} x[b*G + col[e]] * W[e] + bias[s]
// B=64 (== wavefront), G=20000, S=200000, NNZ=2e6.
//
// R6 post-mortem: sort-free LDS-tile RMW kernel regressed (72->149us): the
// per-pair ds_read/ds_write chain is serially dependent (alias ordering) =>
// LDS latency per pair; bank conflicts doubled. Register accumulators +
// broadcast edges (R3's PROC) confirmed as the right structure. REVERTED.
//
// Pipeline (R3-proven, graph-capture safe, all on `stream`):
//   1. transpose x [B,G] -> xTh [G,B] in BF16 (2.56MB, L2-resident gathers)
//   2. pass1: counting sort of 8192-edge chunks into 64-row bins (3125):
//      LDS hist[3584] -> wave-shfl scan -> LDS scatter -> coalesced dump +
//      per-chunk u32 START table.
//   3. compute: one 256-thread block per 64-row bin. Gather ~640 edges from
//      245 runs, 64-row LDS sort (4-replica hist + wave scan), then
//      quad-lockstep PROC with LENGTH-BALANCED QUADS (new vs R3):
//      rows bitonic-sorted by edge count (wave 0, ~100 instrs); quad k
//      takes sorted rows 4k..4k+3 (near-equal counts => zero-pad waste
//      1.5x -> ~1.05x, ~30% of F-phase issue slots removed); quad->wave
//      map k=qd*4+wv deals each wave one quad per length class.
//      16KB transpose-tile epilogue overlays the staging buffer.

#define WAVE 64
#define CHUNK 8192
#define RBITS 6                 // 64 rows per bin
#define BINROWS 64
#define SCAN_PAD 3584           // 512*7 >= nbin+1 = 3126
#define CAP_BIN 896             // max edges/bin: mean 640 + ~10 sigma

#define RL(v, i)  __builtin_amdgcn_readlane((int)(v), (i))

__device__ __forceinline__ int swz(int r, int b) {
    return (r << 6) + (b ^ (r & 63));   // tile[64][64], XOR-swizzled (2-way free)
}

__device__ __forceinline__ unsigned short f2bf(float f) {
    unsigned u = __float_as_uint(f);
    unsigned r = (u + 0x7fffu + ((u >> 16) & 1u)) >> 16;   // RTNE
    return (unsigned short)r;
}

__global__ void transpose64_kernel(const float* __restrict__ x,
                                   unsigned short* __restrict__ xTh, int G) {
    __shared__ float tile[64][65];
    const int t  = threadIdx.x;
    const int g0 = blockIdx.x * 64;
    {
        const int j  = t & 63;
        const int b0 = t >> 6;
        if (g0 + j < G) {
            #pragma unroll
            for (int it = 0; it < 16; ++it) {
                const int b = b0 + it * 4;
                tile[j][b] = x[(size_t)b * G + g0 + j];
            }
        }
    }
    __syncthreads();
    {
        const int b  = t & 63;
        const int j0 = t >> 6;
        #pragma unroll
        for (int it = 0; it < 16; ++it) {
            const int j = j0 + it * 4;
            if (g0 + j < G) xTh[(size_t)(g0 + j) * WAVE + b] = f2bf(tile[j][b]);
        }
    }
}

// Pass 1: per-chunk counting sort into 64-row bins. All global stores
// coalesced. Record: ((r & 63) << 15) | col.
// segtab[chunk*(nbin+1) + b] = global start of (chunk,bin) run.
__global__ __launch_bounds__(512) void pass1_kernel(
        const int* __restrict__ row, const int* __restrict__ col,
        const float* __restrict__ w, uint2* __restrict__ sedge1,
        unsigned* __restrict__ segtab, int nnz, int nbin) {
    __shared__ __align__(16) uint2 stage[CHUNK];   // 64 KB
    __shared__ int hist[SCAN_PAD];                 // 14 KB
    __shared__ int wpart[8];
    const int t    = threadIdx.x;
    const int lane = t & 63;
    const int wv   = t >> 6;
    const int e0   = blockIdx.x * CHUNK;
    const bool full = (e0 + CHUNK <= nnz);
    const int M    = full ? CHUNK : (nnz - e0);

    for (int j = t; j < SCAN_PAD; j += 512) hist[j] = 0;
    __syncthreads();

    // A) count
    if (full) {
        const int4* rv = (const int4*)(row + e0);
        #pragma unroll
        for (int k = 0; k < CHUNK / 2048; ++k) {
            const int4 r4 = rv[k * 512 + t];
            atomicAdd(&hist[r4.x >> RBITS], 1);
            atomicAdd(&hist[r4.y >> RBITS], 1);
            atomicAdd(&hist[r4.z >> RBITS], 1);
            atomicAdd(&hist[r4.w >> RBITS], 1);
        }
    } else {
        for (int k = 0; k < CHUNK / 512; ++k) {
            const int i = k * 512 + t;
            if (i < M) atomicAdd(&hist[row[e0 + i] >> RBITS], 1);
        }
    }
    __syncthreads();

    // B) scan: thread t owns bins [7t, 7t+7); wave shfl-scan + cross-wave
    {
        int c[7];
        int p = 0;
        #pragma unroll
        for (int j = 0; j < 7; ++j) { c[j] = hist[t * 7 + j]; p += c[j]; }
        int incl = p;
        #pragma unroll
        for (int d = 1; d < 64; d <<= 1) {
            const int u = __shfl_up(incl, d);
            if (lane >= d) incl += u;
        }
        if (lane == 63) wpart[wv] = incl;
        __syncthreads();
        int base = incl - p;
        #pragma unroll
        for (int ww = 0; ww < 8; ++ww)
            if (ww < wv) base += wpart[ww];
        unsigned* st = segtab + (size_t)blockIdx.x * (size_t)(nbin + 1);
        int run = base;
        #pragma unroll
        for (int j = 0; j < 7; ++j) {
            const int bj = t * 7 + j;
            hist[bj] = run;                         // scatter cursor (local)
            if (bj <= nbin) st[bj] = (unsigned)(e0 + run);
            run += c[j];
        }
    }
    __syncthreads();

    // C) scatter into LDS staging (chunk re-read is L2-hot)
    if (full) {
        const int4*   rv = (const int4*)(row + e0);
        const int4*   cv = (const int4*)(col + e0);
        const float4* wf = (const float4*)(w + e0);
        #pragma unroll
        for (int k = 0; k < CHUNK / 2048; ++k) {
            const int4   r4 = rv[k * 512 + t];
            const int4   c4 = cv[k * 512 + t];
            const float4 w4 = wf[k * 512 + t];
            {
                const int pos = atomicAdd(&hist[r4.x >> RBITS], 1);
                stage[pos] = make_uint2(((unsigned)(r4.x & 63) << 15) |
                                        (unsigned)c4.x, __float_as_uint(w4.x));
            }
            {
                const int pos = atomicAdd(&hist[r4.y >> RBITS], 1);
                stage[pos] = make_uint2(((unsigned)(r4.y & 63) << 15) |
                                        (unsigned)c4.y, __float_as_uint(w4.y));
            }
            {
                const int pos = atomicAdd(&hist[r4.z >> RBITS], 1);
                stage[pos] = make_uint2(((unsigned)(r4.z & 63) << 15) |
                                        (unsigned)c4.z, __float_as_uint(w4.z));
            }
            {
                const int pos = atomicAdd(&hist[r4.w >> RBITS], 1);
                stage[pos] = make_uint2(((unsigned)(r4.w & 63) << 15) |
                                        (unsigned)c4.w, __float_as_uint(w4.w));
            }
        }
    } else {
        for (int k = 0; k < CHUNK / 512; ++k) {
            const int i = k * 512 + t;
            if (i < M) {
                const int r = row[e0 + i];
                const int pos = atomicAdd(&hist[r >> RBITS], 1);
                stage[pos] = make_uint2(((unsigned)(r & 63) << 15) |
                                        (unsigned)col[e0 + i],
                                        __float_as_uint(w[e0 + i]));
            }
        }
    }
    __syncthreads();

    // D) coalesced contiguous dump
    {
        const uint4* sg4 = (const uint4*)stage;
        uint4* o4 = (uint4*)(sedge1 + e0);
        for (int j = t; j < (M >> 1); j += 512) o4[j] = sg4[j];
        if ((M & 1) && t == 0) sedge1[e0 + M - 1] = stage[M - 1];
    }
}

// gather+fmac one broadcast edge for one row's accumulator
#define PROC(Er, ar, ii)                                                      \
    {                                                                         \
        const int   k_ = RL((Er).x, (ii));                                    \
        const float w_ = __int_as_float(RL((Er).y, (ii)));                    \
        const float v_ = __uint_as_float(                                     \
            (unsigned)*(const unsigned short*)(xb + k_ + lane2) << 16);       \
        (ar) += v_ * w_;                                                      \
    }

// Compute: one block per 64-row bin. Gather segments -> LDS row-sort ->
// length-balanced quad-lockstep PROC -> 16KB LDS-transpose epilogue.
__global__ __launch_bounds__(256) void compute_kernel(
        const unsigned short* __restrict__ xTh,
        const uint2* __restrict__ sedge1,
        const unsigned* __restrict__ segtab,
        const float* __restrict__ bias,
        float* __restrict__ out, int S, int nchunk, int nbin) {
    __shared__ float tile[64 * 64];        // 16 KB; front doubles as eds1
    __shared__ uint2 eds2[CAP_BIN];        // 7 KB sorted edges
    __shared__ int   rcnt[4][BINROWS];
    __shared__ int   cur[4][BINROWS];
    __shared__ int   rstart[BINROWS], rend[BINROWS];
    __shared__ int   rord[BINROWS];        // rows by edge count (bitonic)
    __shared__ float bls[BINROWS];
    __shared__ int   spart[4];
    uint2* eds1 = (uint2*)tile;            // capacity 2048 >= CAP_BIN; dead
                                           // before first tile write

    const int t    = threadIdx.x;
    const int lane = t & 63;
    const int wv   = t >> 6;               // 0..3

    // bijective chunked XCD swizzle: adjacent bins -> same XCD (L2-local
    // sedge1 runs + shared segtab lines)
    const int q8 = nbin >> 3, r8 = nbin & 7;
    const int xcd = (int)blockIdx.x & 7, off = (int)blockIdx.x >> 3;
    const int b = (xcd < r8 ? xcd * (q8 + 1) : r8 * (q8 + 1) + (xcd - r8) * q8)
                  + off;
    const int r0 = b << RBITS;

    if (t < BINROWS) {
        rcnt[0][t] = 0; rcnt[1][t] = 0; rcnt[2][t] = 0; rcnt[3][t] = 0;
        bls[t] = (r0 + t < S) ? bias[r0 + t] : 0.f;
    }

    // A) per-chunk run fetch (nchunk <= 256: one chunk per thread) + scan
    int myst = 0, myn = 0;
    if (t < nchunk) {
        const unsigned* p = segtab + (size_t)t * (size_t)(nbin + 1) + b;
        const unsigned s0 = p[0];
        myst = (int)s0; myn = (int)(p[1] - s0);
    }
    int incl = myn;
    #pragma unroll
    for (int d = 1; d < 64; d <<= 1) {
        const int u = __shfl_up(incl, d);
        if (lane >= d) incl += u;
    }
    if (lane == 63) spart[wv] = incl;
    __syncthreads();
    int base = incl - myn;
    #pragma unroll
    for (int ww = 0; ww < 4; ++ww)
        if (ww < wv) base += spart[ww];
    int M = spart[0] + spart[1] + spart[2] + spart[3];
    if (M > CAP_BIN) M = CAP_BIN;          // statistically unreachable

    // B) gather this bin's edges into LDS (order within bin irrelevant)
    for (int k = 0; k < myn; ++k) {
        const int p = base + k;
        if (p < CAP_BIN) eds1[p] = sedge1[myst + k];
    }
    __syncthreads();

    // C) row histogram (4 wave-private replicas)
    for (int i = t; i < M; i += 256)
        atomicAdd(&rcnt[wv][eds1[i].x >> 15], 1);
    __syncthreads();

    // D) 64-row scan + per-replica cursor bases + length-sort (wave 0 only)
    if (t < BINROWS) {
        const int c0 = rcnt[0][t], c1 = rcnt[1][t];
        const int c2 = rcnt[2][t], c3 = rcnt[3][t];
        const int tot = c0 + c1 + c2 + c3;
        int inc2 = tot;
        #pragma unroll
        for (int d = 1; d < 64; d <<= 1) {
            const int u = __shfl_up(inc2, d);
            if (lane >= d) inc2 += u;
        }
        const int stt = inc2 - tot;
        rstart[t] = stt;
        rend[t]   = stt + tot;
        cur[0][t] = stt;
        cur[1][t] = stt + c0;
        cur[2][t] = stt + c0 + c1;
        cur[3][t] = stt + c0 + c1 + c2;

        // bitonic sort rows by count (keys unique: (tot<<6)|row)
        int key = (tot << 6) | t;
        #pragma unroll
        for (int k = 2; k <= 64; k <<= 1) {
            #pragma unroll
            for (int j = k >> 1; j > 0; j >>= 1) {
                const int other = __shfl_xor(key, j);
                const bool lower = (lane & j) == 0;
                const bool asc   = (lane & k) == 0;   // k=64: always asc
                bool take = ((other < key) == lower);
                if (!asc) take = !take;
                key = take ? other : key;
            }
        }
        rord[t] = key & 63;    // t-th shortest row
    }
    __syncthreads();

    // E) scatter sorted-by-row; key -> byte offset of bf16 xTh row
    //    (same i-partition per wave as phase C -> replica consistency)
    for (int i = t; i < M; i += 256) {
        const uint2 e = eds1[i];
        const int r = (int)(e.x >> 15);
        const int pos = atomicAdd(&cur[wv][r], 1);
        eds2[pos] = make_uint2((e.x & 0x7fffu) << 7, e.y);
    }
    __syncthreads();

    // F) length-balanced quad-lockstep: quad k2=qd*4+wv takes sorted rows
    //    [4*k2, 4*k2+4) -- near-equal counts => ~5% zero-pad (was ~50%)
    const char* xb = (const char*)xTh;
    const int lane2 = lane * 2;

    #pragma unroll
    for (int qd = 0; qd < 4; ++qd) {
        const int p0 = (qd * 4 + wv) * 4;
        const int rl0 = rord[p0 + 0], rl1 = rord[p0 + 1];
        const int rl2 = rord[p0 + 2], rl3 = rord[p0 + 3];
        int s0 = rstart[rl0], e0g = rend[rl0];
        int s1 = rstart[rl1], e1g = rend[rl1];
        int s2 = rstart[rl2], e2g = rend[rl2];
        int s3 = rstart[rl3], e3g = rend[rl3];
        float a0 = 0.f, a1 = 0.f, a2 = 0.f, a3 = 0.f;
        while ((s0 < e0g) || (s1 < e1g) || (s2 < e2g) || (s3 < e3g)) {
            const int m0 = min(WAVE, e0g - s0);
            const int m1 = min(WAVE, e1g - s1);
            const int m2 = min(WAVE, e2g - s2);
            const int m3 = min(WAVE, e3g - s3);
            uint2 E0 = make_uint2(0u, 0u), E1 = make_uint2(0u, 0u);
            uint2 E2 = make_uint2(0u, 0u), E3 = make_uint2(0u, 0u);
            if (lane < m0) E0 = eds2[s0 + lane];
            if (lane < m1) E1 = eds2[s1 + lane];
            if (lane < m2) E2 = eds2[s2 + lane];
            if (lane < m3) E3 = eds2[s3 + lane];
            const int mm = max(max(m0, m1), max(m2, m3));
            int i = 0;
            for (; i + 2 <= mm; i += 2) {
                PROC(E0, a0, i) PROC(E1, a1, i) PROC(E2, a2, i) PROC(E3, a3, i)
                PROC(E0, a0, i + 1) PROC(E1, a1, i + 1)
                PROC(E2, a2, i + 1) PROC(E3, a3, i + 1)
            }
            if (i < mm) {
                PROC(E0, a0, i) PROC(E1, a1, i) PROC(E2, a2, i) PROC(E3, a3, i)
            }
            s0 += max(m0, 0); s1 += max(m1, 0);
            s2 += max(m2, 0); s3 += max(m3, 0);
        }
        tile[swz(rl0, lane)] = a0 + bls[rl0];
        tile[swz(rl1, lane)] = a1 + bls[rl1];
        tile[swz(rl2, lane)] = a2 + bls[rl2];
        tile[swz(rl3, lane)] = a3 + bls[rl3];
    }
    __syncthreads();

    // G) coalesced epilogue: wave wv -> batches [wv*16, wv*16+16)
    const int srow = r0 + lane;
    #pragma unroll
    for (int k = 0; k < 16; ++k) {
        const int bb = wv * 16 + k;
        if (srow < S) out[(size_t)bb * S + srow] = tile[swz(lane, bb)];
    }
}

extern "C" void kernel_launch(void* const* d_in, const int* in_sizes, int n_in,
                              void* d_out, int out_size, void* d_ws, size_t ws_size,
                              hipStream_t stream) {
    const float* x    = (const float*)d_in[0];
    const float* W    = (const float*)d_in[1];
    const float* bias = (const float*)d_in[2];
    const int*   idx  = (const int*)d_in[3];

    const int NNZ = in_sizes[1];
    const int S   = in_sizes[2];
    const int B   = out_size / S;        // 64
    const int G   = in_sizes[0] / B;     // 20000
    const int* rowi = idx;
    const int* coli = idx + NNZ;
    float* out = (float*)d_out;

    const int nbin   = (S + BINROWS - 1) >> RBITS;        // 3125
    const int nchunk = (NNZ + CHUNK - 1) / CHUNK;         // 245 (<= 256)

    // workspace layout (256B-aligned slabs), ~21.7 MB total
    char* ws = (char*)d_ws;
    size_t o = 0;
    auto alloc = [&](size_t bytes) {
        void* p = ws + o;
        o = (o + bytes + 255) & ~(size_t)255;
        return p;
    };
    unsigned short* xTh = (unsigned short*)alloc((size_t)G * B * sizeof(unsigned short));
    uint2*    sedge1 = (uint2*)   alloc((size_t)NNZ * sizeof(uint2));
    unsigned* segtab = (unsigned*)alloc((size_t)nchunk * (size_t)(nbin + 1) *
                                        sizeof(unsigned));
    (void)ws_size; (void)n_in;

    const int tgrid = (G + 63) / 64;
    transpose64_kernel<<<tgrid, 256, 0, stream>>>(x, xTh, G);

    pass1_kernel<<<nchunk, 512, 0, stream>>>(rowi, coli, W, sedge1, segtab,
                                             NNZ, nbin);
    compute_kernel<<<nbin, 256, 0, stream>>>(xTh, sedge1, segtab, bias,
                                             out, S, nchunk, nbin);
}